// Round 1
// baseline (678.098 us; speedup 1.0000x reference)
//
#include <hip/hip_runtime.h>
#include <hip/hip_fp16.h>
#include <math.h>

// ---------------------------------------------------------------------------
// FusionHead: concat(emb[131072,768], tp[131072,3]) -> LayerNorm(771)
//             -> Linear(771->96) -> GELU(exact erf) -> Linear(96->3)
// Strategy: fold gamma/beta into W1/b1 (prep kernels), f16 MFMA 16x16x32 for
// the 771->96 GEMM (K padded to 800 = 25 steps of 32), epilogue does GELU and
// the tiny 96->3 GEMM via shuffles. One wave per 16 rows, A held in regs.
// ---------------------------------------------------------------------------

typedef _Float16 half8 __attribute__((ext_vector_type(8)));
typedef float floatx4 __attribute__((ext_vector_type(4)));

#define E_DIM 768
#define D_DIM 771
#define H_DIM 96
#define KSTEPS 25              // 25 * 32 = 800 padded K
#define WB_ELEMS (KSTEPS * 6 * 64 * 8)   // fragment-packed W1': 76800 f16

// Pack W1' = gamma[k] * W1[k][n] into MFMA B-fragment order, zero-pad k>=771.
// Layout: wB[t][n0][lane][j], lane needs B[k = t*32 + (lane>>4)*8 + j][n = n0*16 + (lane&15)]
__global__ void pack_w1(const float* __restrict__ w1, const float* __restrict__ gamma,
                        _Float16* __restrict__ wB) {
    int idx = blockIdx.x * 256 + threadIdx.x;   // 300 blocks * 256 = 76800 exact
    int j = idx & 7;
    int l = (idx >> 3) & 63;
    int tn = idx >> 9;          // t*6 + n0
    int t = tn / 6;
    int n0 = tn - t * 6;
    int k = t * 32 + ((l >> 4) << 3) + j;
    int n = n0 * 16 + (l & 15);
    float v = 0.f;
    if (k < D_DIM) v = w1[k * H_DIM + n] * gamma[k];
    wB[idx] = (_Float16)v;
}

// b1'[n] = b1[n] + sum_k beta[k] * W1[k][n]   (grid = 96 blocks, 1 wave each)
__global__ void make_b1p(const float* __restrict__ w1, const float* __restrict__ beta,
                         const float* __restrict__ b1, float* __restrict__ b1p) {
    int n = blockIdx.x;
    int l = threadIdx.x;
    float acc = 0.f;
    for (int k = l; k < D_DIM; k += 64)
        acc += beta[k] * w1[k * H_DIM + n];
#pragma unroll
    for (int d = 1; d < 64; d <<= 1)
        acc += __shfl_xor(acc, d, 64);
    if (l == 0) b1p[n] = acc + b1[n];
}

__global__ __launch_bounds__(256) void fusion_main(
    const float* __restrict__ emb, const float* __restrict__ tp,
    const _Float16* __restrict__ wB, const float* __restrict__ b1p,
    const float* __restrict__ w2, const float* __restrict__ b2,
    float* __restrict__ out)
{
    const int lane = threadIdx.x & 63;
    const int wv = threadIdx.x >> 6;
    const int m = lane & 15;        // row within 16-row tile (A), col n within tile (C)
    const int q = lane >> 4;        // quad: k-offset group (A/B), row group (C)
    const int rowBase = blockIdx.x * 64 + wv * 16;
    const long r = (long)(rowBase + m);
    const float* erow = emb + r * (long)E_DIM;

    // ---- pass 1: load raw row slice, accumulate stats, stash f16 in regs ----
    half8 areg[KSTEPS];
    float sum0 = 0.f, sum1 = 0.f, ss0 = 0.f, ss1 = 0.f;
#pragma unroll
    for (int t = 0; t < 24; ++t) {
        floatx4 x0 = *(const floatx4*)(erow + t * 32 + q * 8);
        floatx4 x1 = *(const floatx4*)(erow + t * 32 + q * 8 + 4);
        sum0 += (x0.x + x0.y) + (x0.z + x0.w);
        sum1 += (x1.x + x1.y) + (x1.z + x1.w);
        ss0 += x0.x * x0.x; ss0 += x0.y * x0.y; ss0 += x0.z * x0.z; ss0 += x0.w * x0.w;
        ss1 += x1.x * x1.x; ss1 += x1.y * x1.y; ss1 += x1.z * x1.z; ss1 += x1.w * x1.w;
        half8 a;
        a[0] = (_Float16)x0.x; a[1] = (_Float16)x0.y; a[2] = (_Float16)x0.z; a[3] = (_Float16)x0.w;
        a[4] = (_Float16)x1.x; a[5] = (_Float16)x1.y; a[6] = (_Float16)x1.z; a[7] = (_Float16)x1.w;
        areg[t] = a;
    }
    // t = 24: k in [768 + q*8, 768 + q*8 + 8). Only q==0 carries tree_probs, rest pad 0.
    {
        float v0 = 0.f, v1 = 0.f, v2 = 0.f;
        if (q == 0) {
            const float* tpr = tp + r * 3;
            v0 = tpr[0]; v1 = tpr[1]; v2 = tpr[2];
        }
        sum0 += (v0 + v1) + v2;
        ss0 += v0 * v0; ss0 += v1 * v1; ss0 += v2 * v2;
        half8 a = {(_Float16)v0, (_Float16)v1, (_Float16)v2,
                   (_Float16)0.f, (_Float16)0.f, (_Float16)0.f, (_Float16)0.f, (_Float16)0.f};
        areg[24] = a;
    }

    // ---- row stats: butterfly over the 4 quads holding the same row ----
    float sum = (sum0 + sum1), ss = (ss0 + ss1);
    sum += __shfl_xor(sum, 16, 64);  ss += __shfl_xor(ss, 16, 64);
    sum += __shfl_xor(sum, 32, 64);  ss += __shfl_xor(ss, 32, 64);
    const float inv_n = 1.0f / 771.0f;
    float mean = sum * inv_n;
    float var = ss * inv_n - mean * mean;
    float sc = rsqrtf(var + 1e-5f);
    float off = -mean * sc;

    // ---- normalize in packed f16: a = a*s + c (gamma/beta already in W1'/b1') ----
    const _Float16 sh = (_Float16)sc;
    const _Float16 ch = (_Float16)off;
#pragma unroll
    for (int t = 0; t < KSTEPS; ++t)
        areg[t] = areg[t] * sh + ch;

    // ---- GEMM1: x[16,800] @ W1'[800,96] via 150 MFMAs, B frags from L2 ----
    const half8* __restrict__ wB8 = (const half8*)wB;
    floatx4 acc[6];
#pragma unroll
    for (int n0 = 0; n0 < 6; ++n0) acc[n0] = (floatx4){0.f, 0.f, 0.f, 0.f};
#pragma unroll
    for (int t = 0; t < KSTEPS; ++t) {
#pragma unroll
        for (int n0 = 0; n0 < 6; ++n0) {
            half8 b = wB8[(t * 6 + n0) * 64 + lane];
            acc[n0] = __builtin_amdgcn_mfma_f32_16x16x32_f16(areg[t], b, acc[n0], 0, 0, 0);
        }
    }

    // ---- epilogue: +b1', exact GELU, 96->3 GEMM, butterfly-reduce over 16 lanes ----
    // C layout: col n = n0*16 + (lane&15), row = q*4 + reg.
    float b1v[6];
    float w2v[6][3];
#pragma unroll
    for (int n0 = 0; n0 < 6; ++n0) {
        int n = n0 * 16 + m;
        b1v[n0] = b1p[n];
        w2v[n0][0] = w2[n * 3 + 0];
        w2v[n0][1] = w2[n * 3 + 1];
        w2v[n0][2] = w2[n * 3 + 2];
    }
    const float kInvSqrt2 = 0.70710678118654752f;
#pragma unroll
    for (int reg = 0; reg < 4; ++reg) {
        float r0 = 0.f, r1 = 0.f, r2 = 0.f;
#pragma unroll
        for (int n0 = 0; n0 < 6; ++n0) {
            float h = acc[n0][reg] + b1v[n0];
            h = 0.5f * h * (1.0f + erff(h * kInvSqrt2));
            r0 += h * w2v[n0][0];
            r1 += h * w2v[n0][1];
            r2 += h * w2v[n0][2];
        }
#pragma unroll
        for (int d = 1; d < 16; d <<= 1) {
            r0 += __shfl_xor(r0, d, 64);
            r1 += __shfl_xor(r1, d, 64);
            r2 += __shfl_xor(r2, d, 64);
        }
        if (m == 0) {
            long row = (long)rowBase + q * 4 + reg;
            out[row * 3 + 0] = r0 + b2[0];
            out[row * 3 + 1] = r1 + b2[1];
            out[row * 3 + 2] = r2 + b2[2];
        }
    }
}

extern "C" void kernel_launch(void* const* d_in, const int* in_sizes, int n_in,
                              void* d_out, int out_size, void* d_ws, size_t ws_size,
                              hipStream_t stream) {
    const float* emb   = (const float*)d_in[0];   // [131072,768]
    const float* tp    = (const float*)d_in[1];   // [131072,3]
    const float* gamma = (const float*)d_in[2];   // [771]
    const float* beta  = (const float*)d_in[3];   // [771]
    const float* w1    = (const float*)d_in[4];   // [771,96]
    const float* b1    = (const float*)d_in[5];   // [96]
    const float* w2    = (const float*)d_in[6];   // [96,3]
    const float* b2    = (const float*)d_in[7];   // [3]
    float* out = (float*)d_out;

    _Float16* wB = (_Float16*)d_ws;                                 // 153600 B
    float* b1p = (float*)((char*)d_ws + WB_ELEMS * sizeof(_Float16)); // 384 B

    hipLaunchKernelGGL(pack_w1, dim3(WB_ELEMS / 256), dim3(256), 0, stream, w1, gamma, wB);
    hipLaunchKernelGGL(make_b1p, dim3(H_DIM), dim3(64), 0, stream, w1, beta, b1, b1p);
    hipLaunchKernelGGL(fusion_main, dim3(131072 / 64), dim3(256), 0, stream,
                       emb, tp, wB, b1p, w2, b2, out);
}

// Round 2
// 637.927 us; speedup vs baseline: 1.0630x; 1.0630x over previous
//
#include <hip/hip_runtime.h>
#include <hip/hip_fp16.h>
#include <math.h>

// ---------------------------------------------------------------------------
// FusionHead: concat(emb[131072,768], tp[131072,3]) -> LayerNorm(771)
//             -> Linear(771->96) -> GELU(exact erf) -> Linear(96->3)
//
// R1 key idea: LN->GEMM is linear in x, so MFMA raw f16 values while streaming
// and apply the per-row affine fix in the epilogue:
//   ((x-mu)*s) @ W' = s*(x @ W') - s*mu*colsum(W')
// with W'[k][n] = gamma[k]*W1[k][n], colsum[n] = sum_k W'[k][n],
//      b1'[n]  = b1[n] + beta @ W1.
// This removes the 100-VGPR A-register array that was killing occupancy and
// load-overlap in R0 (23% occ, 9.7% VALUBusy, 767 GB/s).
// ---------------------------------------------------------------------------

typedef _Float16 half8 __attribute__((ext_vector_type(8)));
typedef float floatx4 __attribute__((ext_vector_type(4)));

#define E_DIM 768
#define D_DIM 771
#define H_DIM 96
#define KSTEPS 25              // 25 * 32 = 800 padded K
#define WB_ELEMS (KSTEPS * 6 * 64 * 8)   // fragment-packed W1': 76800 f16

// Pack W1' = gamma[k] * W1[k][n] into MFMA B-fragment order, zero-pad k>=771.
// Layout: wB[t][n0][lane][j]; lane needs B[k = t*32 + (lane>>4)*8 + j][n = n0*16 + (lane&15)]
__global__ void pack_w1(const float* __restrict__ w1, const float* __restrict__ gamma,
                        _Float16* __restrict__ wB) {
    int idx = blockIdx.x * 256 + threadIdx.x;   // 300 blocks * 256 = 76800 exact
    int j = idx & 7;
    int l = (idx >> 3) & 63;
    int tn = idx >> 9;          // t*6 + n0
    int t = tn / 6;
    int n0 = tn - t * 6;
    int k = t * 32 + ((l >> 4) << 3) + j;
    int n = n0 * 16 + (l & 15);
    float v = 0.f;
    if (k < D_DIM) v = w1[k * H_DIM + n] * gamma[k];
    wB[idx] = (_Float16)v;
}

// b1p[n] = b1[n] + sum_k beta[k]*W1[k][n];  colsum[n] = sum_k gamma[k]*W1[k][n]
// grid = 96 blocks, 1 wave each
__global__ void make_vecs(const float* __restrict__ w1, const float* __restrict__ gamma,
                          const float* __restrict__ beta, const float* __restrict__ b1,
                          float* __restrict__ b1p, float* __restrict__ colsum) {
    int n = blockIdx.x;
    int l = threadIdx.x;
    float accb = 0.f, accg = 0.f;
    for (int k = l; k < D_DIM; k += 64) {
        float w = w1[k * H_DIM + n];
        accb += beta[k] * w;
        accg += gamma[k] * w;
    }
#pragma unroll
    for (int d = 1; d < 64; d <<= 1) {
        accb += __shfl_xor(accb, d, 64);
        accg += __shfl_xor(accg, d, 64);
    }
    if (l == 0) { b1p[n] = accb + b1[n]; colsum[n] = accg; }
}

__global__ __launch_bounds__(256) void fusion_main(
    const float* __restrict__ emb, const float* __restrict__ tp,
    const _Float16* __restrict__ wB, const float* __restrict__ b1p,
    const float* __restrict__ colsum,
    const float* __restrict__ w2, const float* __restrict__ b2,
    float* __restrict__ out)
{
    const int lane = threadIdx.x & 63;
    const int wv = threadIdx.x >> 6;
    const int m = lane & 15;        // A: row in 16-row tile; C: col n within tile
    const int q = lane >> 4;        // A/B: k-group; C: row group
    const int rowBase = blockIdx.x * 64 + wv * 16;
    const long r = (long)(rowBase + m);
    const float* erow = emb + r * (long)E_DIM;
    const half8* __restrict__ wB8 = (const half8*)wB;

    floatx4 acc[6];
#pragma unroll
    for (int n0 = 0; n0 < 6; ++n0) acc[n0] = (floatx4){0.f, 0.f, 0.f, 0.f};

    // ---- fused stream: load raw A slice, stats, convert, MFMA immediately ----
    float sum = 0.f, ss = 0.f;
#pragma unroll
    for (int t = 0; t < 24; ++t) {
        floatx4 x0 = *(const floatx4*)(erow + t * 32 + q * 8);
        floatx4 x1 = *(const floatx4*)(erow + t * 32 + q * 8 + 4);
        sum += (x0.x + x0.y) + (x0.z + x0.w);
        sum += (x1.x + x1.y) + (x1.z + x1.w);
        ss += x0.x * x0.x; ss += x0.y * x0.y; ss += x0.z * x0.z; ss += x0.w * x0.w;
        ss += x1.x * x1.x; ss += x1.y * x1.y; ss += x1.z * x1.z; ss += x1.w * x1.w;
        half8 a;
        a[0] = (_Float16)x0.x; a[1] = (_Float16)x0.y; a[2] = (_Float16)x0.z; a[3] = (_Float16)x0.w;
        a[4] = (_Float16)x1.x; a[5] = (_Float16)x1.y; a[6] = (_Float16)x1.z; a[7] = (_Float16)x1.w;
#pragma unroll
        for (int n0 = 0; n0 < 6; ++n0)
            acc[n0] = __builtin_amdgcn_mfma_f32_16x16x32_f16(a, wB8[(t * 6 + n0) * 64 + lane], acc[n0], 0, 0, 0);
    }
    // t = 24: k in [768+q*8, 768+q*8+8). Only q==0 carries tree_probs; rest pad 0.
    {
        float v0 = 0.f, v1 = 0.f, v2 = 0.f;
        if (q == 0) {
            const float* tpr = tp + r * 3;
            v0 = tpr[0]; v1 = tpr[1]; v2 = tpr[2];
        }
        sum += (v0 + v1) + v2;
        ss += v0 * v0; ss += v1 * v1; ss += v2 * v2;
        half8 a = {(_Float16)v0, (_Float16)v1, (_Float16)v2,
                   (_Float16)0.f, (_Float16)0.f, (_Float16)0.f, (_Float16)0.f, (_Float16)0.f};
#pragma unroll
        for (int n0 = 0; n0 < 6; ++n0)
            acc[n0] = __builtin_amdgcn_mfma_f32_16x16x32_f16(a, wB8[(24 * 6 + n0) * 64 + lane], acc[n0], 0, 0, 0);
    }

    // ---- row stats: reduce over the 4 quads holding the same row ----
    sum += __shfl_xor(sum, 16, 64);  ss += __shfl_xor(ss, 16, 64);
    sum += __shfl_xor(sum, 32, 64);  ss += __shfl_xor(ss, 32, 64);
    const float inv_n = 1.0f / 771.0f;
    float mean = sum * inv_n;
    float var = ss * inv_n - mean * mean;
    float sc = rsqrtf(var + 1e-5f);

    // ---- epilogue: affine LN fix + b1', exact GELU, 96->3 GEMM, reduce ----
    // C layout: col n = n0*16 + m, row = q*4 + reg.
    float b1v[6], csv[6], w2v[6][3];
#pragma unroll
    for (int n0 = 0; n0 < 6; ++n0) {
        int n = n0 * 16 + m;
        b1v[n0] = b1p[n];
        csv[n0] = colsum[n];
        w2v[n0][0] = w2[n * 3 + 0];
        w2v[n0][1] = w2[n * 3 + 1];
        w2v[n0][2] = w2[n * 3 + 2];
    }
    const float kInvSqrt2 = 0.70710678118654752f;
#pragma unroll
    for (int reg = 0; reg < 4; ++reg) {
        int row = q * 4 + reg;
        float mu_r = __shfl(mean, row, 64);   // lane 'row' has m==row
        float sc_r = __shfl(sc, row, 64);
        float r0 = 0.f, r1 = 0.f, r2 = 0.f;
#pragma unroll
        for (int n0 = 0; n0 < 6; ++n0) {
            float h = sc_r * (acc[n0][reg] - mu_r * csv[n0]) + b1v[n0];
            h = 0.5f * h * (1.0f + erff(h * kInvSqrt2));
            r0 += h * w2v[n0][0];
            r1 += h * w2v[n0][1];
            r2 += h * w2v[n0][2];
        }
#pragma unroll
        for (int d = 1; d < 16; d <<= 1) {
            r0 += __shfl_xor(r0, d, 64);
            r1 += __shfl_xor(r1, d, 64);
            r2 += __shfl_xor(r2, d, 64);
        }
        if (m == 0) {
            long orow = (long)rowBase + row;
            out[orow * 3 + 0] = r0 + b2[0];
            out[orow * 3 + 1] = r1 + b2[1];
            out[orow * 3 + 2] = r2 + b2[2];
        }
    }
}

extern "C" void kernel_launch(void* const* d_in, const int* in_sizes, int n_in,
                              void* d_out, int out_size, void* d_ws, size_t ws_size,
                              hipStream_t stream) {
    const float* emb   = (const float*)d_in[0];   // [131072,768]
    const float* tp    = (const float*)d_in[1];   // [131072,3]
    const float* gamma = (const float*)d_in[2];   // [771]
    const float* beta  = (const float*)d_in[3];   // [771]
    const float* w1    = (const float*)d_in[4];   // [771,96]
    const float* b1    = (const float*)d_in[5];   // [96]
    const float* w2    = (const float*)d_in[6];   // [96,3]
    const float* b2    = (const float*)d_in[7];   // [3]
    float* out = (float*)d_out;

    _Float16* wB = (_Float16*)d_ws;                                    // 153600 B
    float* b1p    = (float*)((char*)d_ws + WB_ELEMS * sizeof(_Float16));   // 384 B
    float* colsum = b1p + H_DIM;                                           // 384 B

    hipLaunchKernelGGL(pack_w1, dim3(WB_ELEMS / 256), dim3(256), 0, stream, w1, gamma, wB);
    hipLaunchKernelGGL(make_vecs, dim3(H_DIM), dim3(64), 0, stream, w1, gamma, beta, b1, b1p, colsum);
    hipLaunchKernelGGL(fusion_main, dim3(131072 / 64), dim3(256), 0, stream,
                       emb, tp, wB, b1p, colsum, w2, b2, out);
}

// Round 3
// 551.991 us; speedup vs baseline: 1.2285x; 1.1557x over previous
//
#include <hip/hip_runtime.h>
#include <hip/hip_fp16.h>
#include <math.h>

// ---------------------------------------------------------------------------
// FusionHead: concat(emb[131072,768], tp[131072,3]) -> LayerNorm(771)
//             -> Linear(771->96) -> GELU(exact erf) -> Linear(96->3)
//
// R1: fold gamma/beta into W1 (prep kernels); LN is linear in x, so MFMA raw
//     f16 and fix per-row in the epilogue: ((x-mu)*s)@W' = s*(x@W') - s*mu*colsum.
// R3: B-fragments are identical for every wave -> stage them through LDS in
//     5 chunks of 5 K-steps (30 KB). Per-wave global loads drop 198 -> 48;
//     B reads become ds_read_b128. A-loads for a whole chunk are batched into
//     registers first for MLP on the HBM stream. (R2 was latency-bound: each
//     wave streamed 150 KB of B through L1 at L2 latency with ~1 step of MLP.)
// ---------------------------------------------------------------------------

typedef _Float16 half8 __attribute__((ext_vector_type(8)));
typedef float floatx4 __attribute__((ext_vector_type(4)));

#define E_DIM 768
#define D_DIM 771
#define H_DIM 96
#define KSTEPS 25                        // 25 * 32 = 800 padded K
#define CHUNK_T 5                        // K-steps per LDS chunk
#define NCHUNK 5
#define CHUNK_F16 (CHUNK_T * 6 * 64 * 8) // 15360 f16 = 30720 B per chunk
#define WB_ELEMS (KSTEPS * 6 * 64 * 8)   // fragment-packed W1': 76800 f16

// Pack W1' = gamma[k] * W1[k][n] into MFMA B-fragment order, zero-pad k>=771.
// Layout: wB[t][n0][lane][j]; lane needs B[k = t*32 + (lane>>4)*8 + j][n = n0*16 + (lane&15)]
__global__ void pack_w1(const float* __restrict__ w1, const float* __restrict__ gamma,
                        _Float16* __restrict__ wB) {
    int idx = blockIdx.x * 256 + threadIdx.x;   // 300 blocks * 256 = 76800 exact
    int j = idx & 7;
    int l = (idx >> 3) & 63;
    int tn = idx >> 9;          // t*6 + n0
    int t = tn / 6;
    int n0 = tn - t * 6;
    int k = t * 32 + ((l >> 4) << 3) + j;
    int n = n0 * 16 + (l & 15);
    float v = 0.f;
    if (k < D_DIM) v = w1[k * H_DIM + n] * gamma[k];
    wB[idx] = (_Float16)v;
}

// b1p[n] = b1[n] + sum_k beta[k]*W1[k][n];  colsum[n] = sum_k gamma[k]*W1[k][n]
__global__ void make_vecs(const float* __restrict__ w1, const float* __restrict__ gamma,
                          const float* __restrict__ beta, const float* __restrict__ b1,
                          float* __restrict__ b1p, float* __restrict__ colsum) {
    int n = blockIdx.x;
    int l = threadIdx.x;
    float accb = 0.f, accg = 0.f;
    for (int k = l; k < D_DIM; k += 64) {
        float w = w1[k * H_DIM + n];
        accb += beta[k] * w;
        accg += gamma[k] * w;
    }
#pragma unroll
    for (int d = 1; d < 64; d <<= 1) {
        accb += __shfl_xor(accb, d, 64);
        accg += __shfl_xor(accg, d, 64);
    }
    if (l == 0) { b1p[n] = accb + b1[n]; colsum[n] = accg; }
}

__global__ __launch_bounds__(256) void fusion_main(
    const float* __restrict__ emb, const float* __restrict__ tp,
    const _Float16* __restrict__ wB, const float* __restrict__ b1p,
    const float* __restrict__ colsum,
    const float* __restrict__ w2, const float* __restrict__ b2,
    float* __restrict__ out)
{
    __shared__ _Float16 bufB[CHUNK_F16];     // 30720 B

    const int tid = threadIdx.x;
    const int lane = tid & 63;
    const int wv = tid >> 6;
    const int m = lane & 15;        // A: row in 16-row tile; C: col n within tile
    const int q = lane >> 4;        // A/B: k-group; C: row group
    const int rowBase = blockIdx.x * 64 + wv * 16;
    const long r = (long)(rowBase + m);
    const float* erow = emb + r * (long)E_DIM;

    floatx4 acc[6];
#pragma unroll
    for (int n0 = 0; n0 < 6; ++n0) acc[n0] = (floatx4){0.f, 0.f, 0.f, 0.f};

    float sum = 0.f, ss = 0.f;

    for (int c = 0; c < NCHUNK; ++c) {
        // ---- stage chunk c of B into LDS (shared by all 4 waves) ----
        __syncthreads();   // previous chunk's ds_reads complete
        {
            const float4* __restrict__ src = (const float4*)(wB + c * CHUNK_F16);
            float4* dst = (float4*)bufB;
#pragma unroll
            for (int rr = 0; rr < 8; ++rr) {
                int g = rr * 256 + tid;            // 1920 granules of 16 B
                if (g < CHUNK_F16 / 8) dst[g] = src[g];
            }
        }
        __syncthreads();   // staging visible

        // ---- batch the chunk's A-loads for MLP ----
        floatx4 xa[CHUNK_T], xb[CHUNK_T];
#pragma unroll
        for (int tt = 0; tt < CHUNK_T; ++tt) {
            int t = c * CHUNK_T + tt;
            if (t < 24) {
                xa[tt] = *(const floatx4*)(erow + t * 32 + q * 8);
                xb[tt] = *(const floatx4*)(erow + t * 32 + q * 8 + 4);
            } else {  // t == 24: only q==0 carries tree_probs; rest pad 0
                float v0 = 0.f, v1 = 0.f, v2 = 0.f;
                if (q == 0) {
                    const float* tpr = tp + r * 3;
                    v0 = tpr[0]; v1 = tpr[1]; v2 = tpr[2];
                }
                xa[tt] = (floatx4){v0, v1, v2, 0.f};
                xb[tt] = (floatx4){0.f, 0.f, 0.f, 0.f};
            }
        }

        // ---- stats + convert + MFMA against LDS B ----
#pragma unroll
        for (int tt = 0; tt < CHUNK_T; ++tt) {
            floatx4 x0 = xa[tt], x1 = xb[tt];
            sum += (x0.x + x0.y) + (x0.z + x0.w);
            sum += (x1.x + x1.y) + (x1.z + x1.w);
            ss += x0.x * x0.x; ss += x0.y * x0.y; ss += x0.z * x0.z; ss += x0.w * x0.w;
            ss += x1.x * x1.x; ss += x1.y * x1.y; ss += x1.z * x1.z; ss += x1.w * x1.w;
            half8 a;
            a[0] = (_Float16)x0.x; a[1] = (_Float16)x0.y; a[2] = (_Float16)x0.z; a[3] = (_Float16)x0.w;
            a[4] = (_Float16)x1.x; a[5] = (_Float16)x1.y; a[6] = (_Float16)x1.z; a[7] = (_Float16)x1.w;
#pragma unroll
            for (int n0 = 0; n0 < 6; ++n0) {
                half8 b = *(const half8*)&bufB[((tt * 6 + n0) * 64 + lane) * 8];
                acc[n0] = __builtin_amdgcn_mfma_f32_16x16x32_f16(a, b, acc[n0], 0, 0, 0);
            }
        }
    }

    // ---- row stats: reduce over the 4 quads holding the same row ----
    sum += __shfl_xor(sum, 16, 64);  ss += __shfl_xor(ss, 16, 64);
    sum += __shfl_xor(sum, 32, 64);  ss += __shfl_xor(ss, 32, 64);
    const float inv_n = 1.0f / 771.0f;
    float mean = sum * inv_n;
    float var = ss * inv_n - mean * mean;
    float sc = rsqrtf(var + 1e-5f);

    // ---- epilogue: affine LN fix + b1', exact GELU, 96->3 GEMM, reduce ----
    // C layout: col n = n0*16 + m, row = q*4 + reg.
    float b1v[6], csv[6], w2v[6][3];
#pragma unroll
    for (int n0 = 0; n0 < 6; ++n0) {
        int n = n0 * 16 + m;
        b1v[n0] = b1p[n];
        csv[n0] = colsum[n];
        w2v[n0][0] = w2[n * 3 + 0];
        w2v[n0][1] = w2[n * 3 + 1];
        w2v[n0][2] = w2[n * 3 + 2];
    }
    const float kInvSqrt2 = 0.70710678118654752f;
#pragma unroll
    for (int reg = 0; reg < 4; ++reg) {
        int row = q * 4 + reg;
        float mu_r = __shfl(mean, row, 64);   // lane 'row' has m==row
        float sc_r = __shfl(sc, row, 64);
        float r0 = 0.f, r1 = 0.f, r2 = 0.f;
#pragma unroll
        for (int n0 = 0; n0 < 6; ++n0) {
            float h = sc_r * (acc[n0][reg] - mu_r * csv[n0]) + b1v[n0];
            h = 0.5f * h * (1.0f + erff(h * kInvSqrt2));
            r0 += h * w2v[n0][0];
            r1 += h * w2v[n0][1];
            r2 += h * w2v[n0][2];
        }
#pragma unroll
        for (int d = 1; d < 16; d <<= 1) {
            r0 += __shfl_xor(r0, d, 64);
            r1 += __shfl_xor(r1, d, 64);
            r2 += __shfl_xor(r2, d, 64);
        }
        if (m == 0) {
            long orow = (long)rowBase + row;
            out[orow * 3 + 0] = r0 + b2[0];
            out[orow * 3 + 1] = r1 + b2[1];
            out[orow * 3 + 2] = r2 + b2[2];
        }
    }
}

extern "C" void kernel_launch(void* const* d_in, const int* in_sizes, int n_in,
                              void* d_out, int out_size, void* d_ws, size_t ws_size,
                              hipStream_t stream) {
    const float* emb   = (const float*)d_in[0];   // [131072,768]
    const float* tp    = (const float*)d_in[1];   // [131072,3]
    const float* gamma = (const float*)d_in[2];   // [771]
    const float* beta  = (const float*)d_in[3];   // [771]
    const float* w1    = (const float*)d_in[4];   // [771,96]
    const float* b1    = (const float*)d_in[5];   // [96]
    const float* w2    = (const float*)d_in[6];   // [96,3]
    const float* b2    = (const float*)d_in[7];   // [3]
    float* out = (float*)d_out;

    _Float16* wB = (_Float16*)d_ws;                                        // 153600 B
    float* b1p    = (float*)((char*)d_ws + WB_ELEMS * sizeof(_Float16));   // 384 B
    float* colsum = b1p + H_DIM;                                           // 384 B

    hipLaunchKernelGGL(pack_w1, dim3(WB_ELEMS / 256), dim3(256), 0, stream, w1, gamma, wB);
    hipLaunchKernelGGL(make_vecs, dim3(H_DIM), dim3(64), 0, stream, w1, gamma, beta, b1, b1p, colsum);
    hipLaunchKernelGGL(fusion_main, dim3(131072 / 64), dim3(256), 0, stream,
                       emb, tp, wB, b1p, colsum, w2, b2, out);
}